// Round 10
// baseline (191.261 us; speedup 1.0000x reference)
//
#include <hip/hip_runtime.h>
#include <hip/hip_bf16.h>
#include <stdint.h>

// SymmetricLoss: symmetric InfoNCE over cosine logits.
// loss = mean_i[ 0.5*(log rowsum_i + log colsum_i) - S_ii ],
// S = Xn·Ynᵀ / tau.  |S|<=2 so exp needs no max subtraction.
//
// GEMM (R10 = R9 with 8 waves/block for TLP):
//  - mfma_f32_32x32x16_bf16, 128x256 block, 512 threads (8 waves 2Mx4N,
//    64x64/wave), BK=32 double-buffered, 48 KiB LDS -> 2 blocks/CU
//    = 16 waves/CU (4/SIMD) to hide barrier/vmcnt/lgkm bubbles (m114 TLP):
//    R9's per-CU budget showed ~MFMA 66K + LDS ~95K cyc vs 239K wall ->
//    ~40% sync bubbles with only 8 waves/CU.
//  - Pair-window XOR swizzle (R9, verified: conflicts 1.9e7 -> 6.3e6 =
//    b128 inherent overhead): LDS slot s = lc ^ ((r>>1)&7), staged linear
//    with SOURCE pre-swizzled (rule #21), reads XOR slot bits.

#define NROWS 8192
#define DDIM  512
#define TAU_INV 2.0f

typedef __bf16 bf16x8 __attribute__((ext_vector_type(8)));
typedef __bf16 bf16x4 __attribute__((ext_vector_type(4)));
typedef float  f32x16 __attribute__((ext_vector_type(16)));

__device__ __forceinline__ void gload(const __bf16* src, __bf16* dst) {
  __builtin_amdgcn_global_load_lds((__attribute__((address_space(1))) void*)src,
      (__attribute__((address_space(3))) void*)dst, 16, 0, 0);
}

// ---------------- kernel 1: row-normalize x,y -> bf16 (+ zero accumulators) ----------------
__global__ __launch_bounds__(256) void normalize_kernel(
    const float* __restrict__ x, const float* __restrict__ y,
    __bf16* __restrict__ xn, __bf16* __restrict__ yn,
    float* __restrict__ rowsum, float* __restrict__ colsum,
    float* __restrict__ out) {
  const int idx = blockIdx.x * 256 + (int)threadIdx.x;
  if (idx < NROWS) { rowsum[idx] = 0.0f; colsum[idx] = 0.0f; }
  if (idx == 0) out[0] = 0.0f;

  const int wave = threadIdx.x >> 6;
  const int lane = threadIdx.x & 63;
  const int row  = blockIdx.x * 4 + wave;   // 0..16383: first 8192 = x, rest = y
  const float* src;
  __bf16* dst;
  if (row < NROWS) { src = x + (size_t)row * DDIM;           dst = xn + (size_t)row * DDIM; }
  else             { src = y + (size_t)(row - NROWS) * DDIM; dst = yn + (size_t)(row - NROWS) * DDIM; }

  const float4* s4 = (const float4*)src;
  float4 v0 = s4[lane];
  float4 v1 = s4[lane + 64];
  float ss = v0.x*v0.x + v0.y*v0.y + v0.z*v0.z + v0.w*v0.w
           + v1.x*v1.x + v1.y*v1.y + v1.z*v1.z + v1.w*v1.w;
  #pragma unroll
  for (int off = 1; off < 64; off <<= 1) ss += __shfl_xor(ss, off);
  const float rn = 1.0f / fmaxf(sqrtf(ss), 1e-8f);

  bf16x4 o0, o1;
  o0[0]=(__bf16)(v0.x*rn); o0[1]=(__bf16)(v0.y*rn); o0[2]=(__bf16)(v0.z*rn); o0[3]=(__bf16)(v0.w*rn);
  o1[0]=(__bf16)(v1.x*rn); o1[1]=(__bf16)(v1.y*rn); o1[2]=(__bf16)(v1.z*rn); o1[3]=(__bf16)(v1.w*rn);
  *(bf16x4*)(dst + 4*lane)       = o0;
  *(bf16x4*)(dst + 256 + 4*lane) = o1;
}

// ---------------- kernel 2: fused 128x256-tile GEMM + exp + row/col sums ----------------
// LDS elems: A bufs 2 x 4096 at [0,8192); B bufs 2 x 8192 at [8192,24576). 48 KiB.
__global__ __launch_bounds__(512, 4) void gemm_exp_kernel(
    const __bf16* __restrict__ Xn, const __bf16* __restrict__ Yn,
    float* __restrict__ rowsum, float* __restrict__ colsum,
    float* __restrict__ diag) {
  __shared__ __bf16 sm[24576];   // 48 KiB -> 2 blocks/CU (16 waves)

  const int tid  = threadIdx.x;
  const int lane = tid & 63;
  const int w    = tid >> 6;
  const int wr   = w >> 2;            // 0..1  (64-row half)
  const int wc   = w & 3;             // 0..3  (64-col quarter)

  // XCD-aware swizzle (T1): 2048 blocks, 8 XCDs, bi-fast within an XCD chunk.
  const int id  = blockIdx.x;
  const int swz = (id & 7) * 256 + (id >> 3);
  const int bi  = swz & 63;           // 64 row tiles of 128
  const int bj  = swz >> 6;           // 32 col tiles of 256
  const int Ar = bi * 128;
  const int Br = bj * 256;

  const int l31 = lane & 31;
  const int hi  = lane >> 5;          // 0..1

  // ---- staging source pre-swizzle (involution): thread t -> (srow, sch) ----
  // lc = (t&7) ^ ((t>>3)&7); srow = 2*(t>>3) + (lc>>2); sch = lc&3.
  // 512 threads cover 128 rows x 4 chunks; B staged as two 128-row halves.
  const int lc   = (tid & 7) ^ ((tid >> 3) & 7);
  const int srow = 2 * (tid >> 3) + (lc >> 2);
  const __bf16* PA  = Xn + (size_t)(Ar + srow) * DDIM + (lc & 3) * 8;
  const __bf16* PB  = Yn + (size_t)(Br + srow) * DDIM + (lc & 3) * 8;
  const __bf16* PB2 = PB + (size_t)128 * DDIM;

  // ---- fragment read offsets (bf16 elements), ks=0; ks=1 XORs elem bit 4 ----
  // elem = (l31>>1)*64 + slot*8 [+ rowbase*32], slot = ((l31&1)<<2 | ks<<1 | hi) ^ ((l31>>1)&7)
  const int swk   = (l31 >> 1) & 7;
  const int aoff0 = (l31 >> 1) * 64 + ((((l31 & 1) << 2) + hi) ^ swk) * 8 + wr * 2048;
  const int boff0 = (l31 >> 1) * 64 + ((((l31 & 1) << 2) + hi) ^ swk) * 8 + wc * 2048;

  f32x16 acc[2][2] = {};

  // prologue: stage K-tile 0 into buf 0 (LDS dest linear)
  gload(PA,   sm + tid*8);
  gload(PB,   sm + 8192 + tid*8);
  gload(PB2,  sm + 8192 + 4096 + tid*8);
  __syncthreads();

  #pragma unroll 1
  for (int kt = 0; kt < 16; ++kt) {
    const int buf = kt & 1;
    // stage K-tile kt+1 into the other buffer (issue early; lands by the barrier)
    if (kt < 15) {
      const int ko = (kt + 1) * 32;
      __bf16* da = sm + (buf ^ 1) * 4096;
      __bf16* db = sm + 8192 + (buf ^ 1) * 8192;
      gload(PA  + ko, da + tid*8);
      gload(PB  + ko, db + tid*8);
      gload(PB2 + ko, db + 4096 + tid*8);
    }
    // fragments + MFMA (compiler schedules ds_reads with counted lgkm waits)
    const __bf16* As = sm + buf * 4096;
    const __bf16* Bs = sm + 8192 + buf * 8192;
    #pragma unroll
    for (int ks = 0; ks < 2; ++ks) {
      bf16x8 a[2], b[2];
      #pragma unroll
      for (int mi = 0; mi < 2; ++mi)
        a[mi] = *(const bf16x8*)(As + ((aoff0 + mi*1024) ^ (ks*16)));
      #pragma unroll
      for (int ni = 0; ni < 2; ++ni)
        b[ni] = *(const bf16x8*)(Bs + ((boff0 + ni*1024) ^ (ks*16)));
      #pragma unroll
      for (int mi = 0; mi < 2; ++mi)
        #pragma unroll
        for (int ni = 0; ni < 2; ++ni)
          acc[mi][ni] = __builtin_amdgcn_mfma_f32_32x32x16_bf16(a[mi], b[ni], acc[mi][ni], 0, 0, 0);
    }
    __syncthreads();   // drains vmcnt (stage landed) + lgkm; protects both buffers
  }

  // ---------------- epilogue ----------------
  // 32x32 C/D mapping (verified m74/m101): col = l31, row = (reg&3) + 8*(reg>>2) + 4*hi
  // diag (pre-exp logits): tile contains diagonal iff bj == bi>>1
  if ((bi >> 1) == bj) {
    #pragma unroll
    for (int mi = 0; mi < 2; ++mi)
      #pragma unroll
      for (int ni = 0; ni < 2; ++ni)
        #pragma unroll
        for (int reg = 0; reg < 16; ++reg) {
          const int grow = Ar + wr*64 + mi*32 + (reg&3) + 8*(reg>>2) + 4*hi;
          const int gcol = Br + wc*64 + ni*32 + l31;
          if (grow == gcol) diag[grow] = TAU_INV * acc[mi][ni][reg];
        }
  }

  // exp in place
  #pragma unroll
  for (int mi = 0; mi < 2; ++mi)
    #pragma unroll
    for (int ni = 0; ni < 2; ++ni)
      #pragma unroll
      for (int reg = 0; reg < 16; ++reg)
        acc[mi][ni][reg] = __expf(TAU_INV * acc[mi][ni][reg]);

  // row sums: sum 2 ni + reduce over 32 cols (l31); one row per (mi,reg,hi)
  #pragma unroll
  for (int mi = 0; mi < 2; ++mi) {
    #pragma unroll
    for (int reg = 0; reg < 16; ++reg) {
      float v = acc[mi][0][reg] + acc[mi][1][reg];
      v += __shfl_xor(v, 1);  v += __shfl_xor(v, 2);
      v += __shfl_xor(v, 4);  v += __shfl_xor(v, 8); v += __shfl_xor(v, 16);
      if (l31 == 0) {
        const int grow = Ar + wr*64 + mi*32 + (reg&3) + 8*(reg>>2) + 4*hi;
        atomicAdd(&rowsum[grow], v);
      }
    }
  }
  // col sums: sum 2 mi x 16 regs per lane, fold the two hi-halves (same col)
  #pragma unroll
  for (int ni = 0; ni < 2; ++ni) {
    float v = 0.0f;
    #pragma unroll
    for (int mi = 0; mi < 2; ++mi)
      #pragma unroll
      for (int reg = 0; reg < 16; ++reg)
        v += acc[mi][ni][reg];
    v += __shfl_xor(v, 32);
    if (hi == 0) atomicAdd(&colsum[Br + wc*64 + ni*32 + l31], v);
  }
}

// ---------------- kernel 3: final scalar reduction (32 blocks, atomic) ----------------
__global__ __launch_bounds__(256) void finalize_kernel(
    const float* __restrict__ rowsum, const float* __restrict__ colsum,
    const float* __restrict__ diag, float* __restrict__ out) {
  const int i = blockIdx.x * 256 + (int)threadIdx.x;   // 32*256 == 8192 exactly
  float s = 0.5f * (logf(rowsum[i]) + logf(colsum[i])) - diag[i];
  #pragma unroll
  for (int off = 1; off < 64; off <<= 1) s += __shfl_xor(s, off);
  if ((threadIdx.x & 63) == 0) atomicAdd(out, s * (1.0f / NROWS));
}

extern "C" void kernel_launch(void* const* d_in, const int* in_sizes, int n_in,
                              void* d_out, int out_size, void* d_ws, size_t ws_size,
                              hipStream_t stream) {
  const float* x = (const float*)d_in[0];
  const float* y = (const float*)d_in[1];
  float* out = (float*)d_out;

  char* ws = (char*)d_ws;
  __bf16* Xn = (__bf16*)ws;                               // 8 MB
  __bf16* Yn = Xn + (size_t)NROWS * DDIM;                 // 8 MB
  float* rowsum = (float*)(ws + 2 * (size_t)NROWS * DDIM * sizeof(__bf16));
  float* colsum = rowsum + NROWS;
  float* diag   = colsum + NROWS;

  normalize_kernel<<<(2 * NROWS) / 4, 256, 0, stream>>>(x, y, Xn, Yn, rowsum, colsum, out);
  gemm_exp_kernel<<<2048, 512, 0, stream>>>(Xn, Yn, rowsum, colsum, diag);
  finalize_kernel<<<32, 256, 0, stream>>>(rowsum, colsum, diag, out);
}